// Round 1
// baseline (93.944 us; speedup 1.0000x reference)
//
#include <hip/hip_runtime.h>

// Problem constants (from reference setup_inputs)
#define N_TOK 512    // number of input rows (tokens)
#define IN_F  2048   // in_features (cols of W)
#define OUT_F 2048   // out_features (rows of W)
#define NNZ_MAX_PER_ROW 128

// Static device scratch for transposed x: xT[col][token], 4 MB.
// (Avoids depending on ws_size; rewritten fully every call.)
__device__ float g_xT[IN_F * N_TOK];

// ---------------------------------------------------------------------------
// Kernel 1: transpose x [N_TOK, IN_F] -> xT [IN_F, N_TOK], LDS-tiled 32x32.
// ---------------------------------------------------------------------------
__global__ __launch_bounds__(256) void transpose_x(const float* __restrict__ x) {
    __shared__ float tile[32][33];   // +1 pad: kill 32-way bank conflicts
    const int bx = blockIdx.x;       // col-tile   (IN_F/32 = 64)
    const int by = blockIdx.y;       // token-tile (N_TOK/32 = 16)
    const int tx = threadIdx.x;      // 0..31
    const int ty = threadIdx.y;      // 0..7

    const int col  = bx * 32 + tx;
    const int row0 = by * 32 + ty;
#pragma unroll
    for (int j = 0; j < 32; j += 8) {
        tile[ty + j][tx] = x[(row0 + j) * IN_F + col];   // coalesced read over col
    }
    __syncthreads();

    const int n  = by * 32 + tx;     // token index (contiguous in xT row)
    const int c0 = bx * 32 + ty;     // col index
#pragma unroll
    for (int j = 0; j < 32; j += 8) {
        g_xT[(c0 + j) * N_TOK + n] = tile[tx][ty + j];   // coalesced write over n
    }
}

// ---------------------------------------------------------------------------
// Kernel 2: one block per W-row r. Row's (data, idx) pairs staged in LDS
// (wave-uniform broadcast reads), each thread accumulates 4 tokens via
// float4 loads from xT (fully coalesced, L2-resident).
// ---------------------------------------------------------------------------
__global__ __launch_bounds__(128) void spmm_csr(const float* __restrict__ data,
                                                const int*   __restrict__ indices,
                                                const int*   __restrict__ indptr,
                                                float*       __restrict__ y) {
    const int r = blockIdx.x;        // W row == output feature
    const int t = threadIdx.x;       // 0..127 -> tokens 4t..4t+3

    __shared__ float s_data[NNZ_MAX_PER_ROW];
    __shared__ int   s_idx [NNZ_MAX_PER_ROW];

    const int start = indptr[r];
    const int count = indptr[r + 1] - start;   // 128 for this problem
    if (t < count) {
        s_data[t] = data[start + t];
        s_idx [t] = indices[start + t];
    }
    __syncthreads();

    const float4* __restrict__ xT4 = (const float4*)g_xT;
    float4 acc = make_float4(0.f, 0.f, 0.f, 0.f);

#pragma unroll 4
    for (int k = 0; k < count; ++k) {
        const float  w = s_data[k];
        const float4 v = xT4[s_idx[k] * (N_TOK / 4) + t];  // 1 KB/wave, coalesced
        acc.x += w * v.x;
        acc.y += w * v.y;
        acc.z += w * v.z;
        acc.w += w * v.w;
    }

    // y is [N_TOK, OUT_F]; column-r scatter (4 B per lane). Uncoalesced but
    // only 1M stores total; revisit if profile shows store stalls.
    const int n = 4 * t;
    y[(n + 0) * OUT_F + r] = acc.x;
    y[(n + 1) * OUT_F + r] = acc.y;
    y[(n + 2) * OUT_F + r] = acc.z;
    y[(n + 3) * OUT_F + r] = acc.w;
}

// ---------------------------------------------------------------------------
extern "C" void kernel_launch(void* const* d_in, const int* in_sizes, int n_in,
                              void* d_out, int out_size, void* d_ws, size_t ws_size,
                              hipStream_t stream) {
    const float* x       = (const float*)d_in[0];   // [512, 2048] f32
    const float* data    = (const float*)d_in[1];   // [262144] f32
    const int*   indices = (const int*)  d_in[2];   // [262144] i32
    const int*   indptr  = (const int*)  d_in[3];   // [2049] i32
    float*       y       = (float*)d_out;           // [512, 2048] f32

    dim3 tb(32, 8);
    dim3 tg(IN_F / 32, N_TOK / 32);
    transpose_x<<<tg, tb, 0, stream>>>(x);

    spmm_csr<<<OUT_F, 128, 0, stream>>>(data, indices, indptr, y);
}

// Round 2
// 89.199 us; speedup vs baseline: 1.0532x; 1.0532x over previous
//
#include <hip/hip_runtime.h>

// Problem constants (from reference setup_inputs)
#define N_TOK 512    // tokens
#define IN_F  2048   // in_features
#define OUT_F 2048   // out_features
#define NNZ_ROW 128  // nnz per W row (uniform; indptr = arange*128)

#define ROW_G 16     // W rows per block
#define TOK_G 128    // tokens per block

// xT[col][token] as bf16 bits, 2 MB -> resident in every XCD L2.
__device__ ushort g_xT16[IN_F * N_TOK];

static __device__ __forceinline__ ushort f2bf(float f) {
    // round-to-nearest-even bf16 (inputs are finite normals)
    unsigned u = __float_as_uint(f);
    unsigned r = (u + 0x7fffu + ((u >> 16) & 1u)) >> 16;
    return (ushort)r;
}

// ---------------------------------------------------------------------------
// Kernel 1: transpose + bf16-pack x [N_TOK, IN_F] -> g_xT16 [IN_F, N_TOK].
// ---------------------------------------------------------------------------
__global__ __launch_bounds__(256) void transpose_x(const float* __restrict__ x) {
    __shared__ float tile[32][33];
    const int bx = blockIdx.x;       // col-tile   (IN_F/32 = 64)
    const int by = blockIdx.y;       // token-tile (N_TOK/32 = 16)
    const int tx = threadIdx.x;      // 0..31
    const int ty = threadIdx.y;      // 0..7

    const int col  = bx * 32 + tx;
    const int row0 = by * 32 + ty;
#pragma unroll
    for (int j = 0; j < 32; j += 8)
        tile[ty + j][tx] = x[(row0 + j) * IN_F + col];   // coalesced over col
    __syncthreads();

    const int n  = by * 32 + tx;
    const int c0 = bx * 32 + ty;
#pragma unroll
    for (int j = 0; j < 32; j += 8)
        g_xT16[(c0 + j) * N_TOK + n] = f2bf(tile[tx][ty + j]);  // 64B runs over n
}

// ---------------------------------------------------------------------------
// Kernel 2: block = 16 W-rows x 128 tokens. (idx,weight) pairs staged in LDS
// as int2 (one ds_read_b64/iter, wave-uniform -> readfirstlane -> scalar
// addressing). Gather loads are 4B/lane coalesced bf16x2. Output tile
// transposed through LDS -> 64B-contiguous stores.
// ---------------------------------------------------------------------------
__global__ __launch_bounds__(256) void spmm_csr(const float* __restrict__ data,
                                                const int*   __restrict__ indices,
                                                const int*   __restrict__ indptr,
                                                float*       __restrict__ y) {
    const int rg = blockIdx.x;           // 0..127
    const int tg = blockIdx.y;           // 0..3
    const int r0 = rg * ROW_G;
    const int t  = threadIdx.x;          // 0..255

    __shared__ int2  s_wi[ROW_G * NNZ_ROW];       // .x = col, .y = weight bits (16 KB)
    __shared__ float ytile[TOK_G][ROW_G + 1];     // +1 pad (8.5 KB)

    // ---- stage this block's 16 rows of (idx, weight), coalesced ----
#pragma unroll
    for (int i = 0; i < 8; ++i) {
        const int g    = t + i * 256;             // 0..2047
        const int rl   = g >> 7;                  // local row
        const int off  = g & (NNZ_ROW - 1);
        const int base = indptr[r0 + rl] + off;
        s_wi[g] = make_int2(indices[base], __float_as_int(data[base]));
    }
    __syncthreads();

    const unsigned* __restrict__ xT = (const unsigned*)g_xT16;  // bf16x2 per uint
    const int w = t >> 6;                 // wave 0..3
    const int l = t & 63;                 // lane
    const int tokoff = tg * (TOK_G / 2) + l;   // uint index within a col's row

    // each wave: 4 rows sequentially; lanes cover tokens 2l, 2l+1
#pragma unroll
    for (int rr = 0; rr < 4; ++rr) {
        const int rl = w * 4 + rr;
        const int2* __restrict__ p = &s_wi[rl * NNZ_ROW];
        float a0 = 0.f, a1 = 0.f;
#pragma unroll 8
        for (int k = 0; k < NNZ_ROW; ++k) {
            const int2 wi  = p[k];                                  // ds_read_b64, uniform
            const int  col = __builtin_amdgcn_readfirstlane(wi.x);  // -> SGPR addressing
            const float wt = __int_as_float(__builtin_amdgcn_readfirstlane(wi.y));
            const unsigned u = xT[col * (N_TOK / 2) + tokoff];      // 256 B/wave, coalesced
            a0 += wt * __uint_as_float(u << 16);          // token 2l   (low bf16)
            a1 += wt * __uint_as_float(u & 0xffff0000u);  // token 2l+1 (high bf16)
        }
        ytile[2 * l    ][rl] = a0;   // stride-17 write: worst 2-way conflict (free)
        ytile[2 * l + 1][rl] = a1;
    }
    __syncthreads();

    // ---- coalesced store: 64 B-contiguous feature runs per token ----
    const int n0 = tg * TOK_G;
#pragma unroll
    for (int i = 0; i < 8; ++i) {
        const int g = t + i * 256;     // 0..2047
        const int n = g >> 4;          // token in tile
        const int f = g & (ROW_G - 1); // feature in tile
        y[(n0 + n) * OUT_F + r0 + f] = ytile[n][f];
    }
}

// ---------------------------------------------------------------------------
extern "C" void kernel_launch(void* const* d_in, const int* in_sizes, int n_in,
                              void* d_out, int out_size, void* d_ws, size_t ws_size,
                              hipStream_t stream) {
    const float* x       = (const float*)d_in[0];   // [512, 2048] f32
    const float* data    = (const float*)d_in[1];   // [262144] f32
    const int*   indices = (const int*)  d_in[2];   // [262144] i32
    const int*   indptr  = (const int*)  d_in[3];   // [2049] i32
    float*       y       = (float*)d_out;           // [512, 2048] f32

    dim3 tb(32, 8);
    dim3 tg(IN_F / 32, N_TOK / 32);
    transpose_x<<<tg, tb, 0, stream>>>(x);

    dim3 sg(OUT_F / ROW_G, N_TOK / TOK_G);          // 128 x 4 = 512 blocks
    spmm_csr<<<sg, 256, 0, stream>>>(data, indices, indptr, y);
}

// Round 3
// 82.824 us; speedup vs baseline: 1.1342x; 1.0770x over previous
//
#include <hip/hip_runtime.h>

// Problem constants (from reference setup_inputs)
#define N_TOK 512    // tokens
#define IN_F  2048   // in_features
#define OUT_F 2048   // out_features
#define NNZ_ROW 128  // nnz per W row (uniform)

#define ROW_G 8      // W rows per block (4 waves x 2 rows)
#define TOK_G 256    // tokens per block (64 lanes x 4 tokens via dwordx2)

// xT[col][token] as bf16 bits, 2 MB -> resident in every XCD L2.
__device__ ushort g_xT16[IN_F * N_TOK];

static __device__ __forceinline__ ushort f2bf(float f) {
    unsigned u = __float_as_uint(f);
    unsigned r = (u + 0x7fffu + ((u >> 16) & 1u)) >> 16;
    return (ushort)r;
}

// ---------------------------------------------------------------------------
// Kernel 1: transpose + bf16-pack x [N_TOK, IN_F] -> g_xT16 [IN_F, N_TOK].
// ---------------------------------------------------------------------------
__global__ __launch_bounds__(256) void transpose_x(const float* __restrict__ x) {
    __shared__ float tile[32][33];
    const int bx = blockIdx.x;       // col-tile   (IN_F/32 = 64)
    const int by = blockIdx.y;       // token-tile (N_TOK/32 = 16)
    const int tx = threadIdx.x;      // 0..31
    const int ty = threadIdx.y;      // 0..7

    const int col  = bx * 32 + tx;
    const int row0 = by * 32 + ty;
#pragma unroll
    for (int j = 0; j < 32; j += 8)
        tile[ty + j][tx] = x[(row0 + j) * IN_F + col];
    __syncthreads();

    const int n  = by * 32 + tx;
    const int c0 = bx * 32 + ty;
#pragma unroll
    for (int j = 0; j < 32; j += 8)
        g_xT16[(c0 + j) * N_TOK + n] = f2bf(tile[tx][ty + j]);
}

// ---------------------------------------------------------------------------
// Kernel 2: block = 8 W-rows x 256 tokens. Each wave owns 2 rows; per k the
// wave does one dwordx2 gather (512 B, coalesced, L2-resident) covering all
// 256 tokens (4/lane). (col,weight) pairs staged in LDS with PRE-SCALED
// column offsets; wave-uniform -> readfirstlane -> scalar addressing.
// Output tile through LDS (ds_write_b128, conflict-free) -> coalesced stores.
// ---------------------------------------------------------------------------
__global__ __launch_bounds__(256) void spmm_csr(const float* __restrict__ data,
                                                const int*   __restrict__ indices,
                                                const int*   __restrict__ indptr,
                                                float*       __restrict__ y) {
    const int rg = blockIdx.x;           // 0..255
    const int tg = blockIdx.y;           // 0..1
    const int r0 = rg * ROW_G;
    const int t  = threadIdx.x;          // 0..255

    __shared__ int2  s_wi[ROW_G * NNZ_ROW];   // .x = col*(N_TOK/4), .y = w bits (8 KB)
    __shared__ float ytile[ROW_G][TOK_G + 4]; // pitch 260: readback conflict-free (8.3 KB)

    // ---- stage 8 rows of (scaled col, weight), coalesced ----
#pragma unroll
    for (int i = 0; i < 4; ++i) {
        const int g    = t + i * 256;             // 0..1023
        const int rl   = g >> 7;
        const int off  = g & (NNZ_ROW - 1);
        const int base = indptr[r0 + rl] + off;
        s_wi[g] = make_int2(indices[base] * (N_TOK / 4), __float_as_int(data[base]));
    }
    __syncthreads();

    const uint2* __restrict__ xT2 = (const uint2*)g_xT16;  // 4 bf16 tokens per uint2
    const int w = t >> 6;                  // wave 0..3
    const int l = t & 63;                  // lane
    const int tokoff = tg * (TOK_G / 4) + l;   // uint2 index within a col's row

#pragma unroll
    for (int rr = 0; rr < 2; ++rr) {
        const int rl = w * 2 + rr;
        const int2* __restrict__ p = &s_wi[rl * NNZ_ROW];
        float4 acc = make_float4(0.f, 0.f, 0.f, 0.f);
#pragma unroll 8
        for (int k = 0; k < NNZ_ROW; ++k) {
            const int2 wi  = p[k];                                   // uniform ds_read_b64
            const int  off = __builtin_amdgcn_readfirstlane(wi.x);   // pre-scaled col
            const float wt = __int_as_float(__builtin_amdgcn_readfirstlane(wi.y));
            const uint2 u  = xT2[off + tokoff];                      // 512 B/wave
            acc.x += wt * __uint_as_float(u.x << 16);
            acc.y += wt * __uint_as_float(u.x & 0xffff0000u);
            acc.z += wt * __uint_as_float(u.y << 16);
            acc.w += wt * __uint_as_float(u.y & 0xffff0000u);
        }
        // tokens 4l..4l+3 of this group, feature rl: one conflict-free b128 write
        *(float4*)&ytile[rl][4 * l] = acc;
    }
    __syncthreads();

    // ---- coalesced store: token n gets features r0..r0+7 (32 B runs) ----
    const int n0 = tg * TOK_G;
#pragma unroll
    for (int i = 0; i < 8; ++i) {
        const int g = t + i * 256;       // 0..2047
        const int n = g >> 3;            // token in tile
        const int f = g & (ROW_G - 1);   // feature in tile
        // readback banks: (260*f + n) % 32 = (4f + n) % 32 -> <=2-way (free)
        y[(n0 + n) * OUT_F + r0 + f] = ytile[f][n];
    }
}

// ---------------------------------------------------------------------------
extern "C" void kernel_launch(void* const* d_in, const int* in_sizes, int n_in,
                              void* d_out, int out_size, void* d_ws, size_t ws_size,
                              hipStream_t stream) {
    const float* x       = (const float*)d_in[0];   // [512, 2048] f32
    const float* data    = (const float*)d_in[1];   // [262144] f32
    const int*   indices = (const int*)  d_in[2];   // [262144] i32
    const int*   indptr  = (const int*)  d_in[3];   // [2049] i32
    float*       y       = (float*)d_out;           // [512, 2048] f32

    dim3 tb(32, 8);
    dim3 tg(IN_F / 32, N_TOK / 32);
    transpose_x<<<tg, tb, 0, stream>>>(x);

    dim3 sg(OUT_F / ROW_G, N_TOK / TOK_G);          // 256 x 2 = 512 blocks
    spmm_csr<<<sg, 256, 0, stream>>>(data, indices, indptr, y);
}

// Round 4
// 81.959 us; speedup vs baseline: 1.1462x; 1.0106x over previous
//
#include <hip/hip_runtime.h>

// Problem constants (from reference setup_inputs)
#define N_TOK 512    // tokens
#define IN_F  2048   // in_features
#define OUT_F 2048   // out_features
#define NNZ_ROW 128  // nnz per W row (uniform)

#define ROW_G 4      // W rows per block (4 waves x 1 row)
#define TOK_G 256    // tokens per block (64 lanes x 4 tokens via dwordx2)

// xT[col][token] as bf16 bits, 2 MB -> resident in every XCD L2.
__device__ ushort g_xT16[IN_F * N_TOK];

static __device__ __forceinline__ ushort f2bf(float f) {
    unsigned u = __float_as_uint(f);
    unsigned r = (u + 0x7fffu + ((u >> 16) & 1u)) >> 16;
    return (ushort)r;
}

// ---------------------------------------------------------------------------
// Kernel 1: transpose + bf16-pack x [N_TOK, IN_F] -> g_xT16 [IN_F, N_TOK].
// (~1.3 us; known-correct from R2/R3, unchanged.)
// ---------------------------------------------------------------------------
__global__ __launch_bounds__(256) void transpose_x(const float* __restrict__ x) {
    __shared__ float tile[32][33];
    const int bx = blockIdx.x;       // col-tile   (IN_F/32 = 64)
    const int by = blockIdx.y;       // token-tile (N_TOK/32 = 16)
    const int tx = threadIdx.x;      // 0..31
    const int ty = threadIdx.y;      // 0..7

    const int col  = bx * 32 + tx;
    const int row0 = by * 32 + ty;
#pragma unroll
    for (int j = 0; j < 32; j += 8)
        tile[ty + j][tx] = x[(row0 + j) * IN_F + col];
    __syncthreads();

    const int n  = by * 32 + tx;
    const int c0 = bx * 32 + ty;
#pragma unroll
    for (int j = 0; j < 32; j += 8)
        g_xT16[(c0 + j) * N_TOK + n] = f2bf(tile[tx][ty + j]);
}

// ---------------------------------------------------------------------------
// Kernel 2: block = 4 W-rows x 256 tokens, each wave owns ONE row.
// 1024 blocks -> 4 blocks/CU -> 4 waves/SIMD; unroll 16 -> up to 8 KB of
// gather loads in flight per wave (32 KB/SIMD) to stay L2-BW-bound, not
// latency-bound. Gather = dwordx2 (512 B/wave, coalesced, L2-resident).
// High-half bf16 unpack uses the raw dword (garbage low bits < bf16 ulp).
// ---------------------------------------------------------------------------
__global__ __launch_bounds__(256) void spmm_csr(const float* __restrict__ data,
                                                const int*   __restrict__ indices,
                                                const int*   __restrict__ indptr,
                                                float*       __restrict__ y) {
    const int rg = blockIdx.x;           // 0..511
    const int tg = blockIdx.y;           // 0..1
    const int r0 = rg * ROW_G;
    const int t  = threadIdx.x;          // 0..255

    __shared__ int2  s_wi[ROW_G * NNZ_ROW];   // .x = col*(N_TOK/4), .y = w bits (4 KB)
    __shared__ float ytile[ROW_G][TOK_G + 4]; // pitch 260 (4.1 KB)

    // ---- stage 4 rows of (scaled col, weight), coalesced ----
#pragma unroll
    for (int i = 0; i < 2; ++i) {
        const int g    = t + i * 256;             // 0..511
        const int rl   = g >> 7;
        const int off  = g & (NNZ_ROW - 1);
        const int base = indptr[r0 + rl] + off;
        s_wi[g] = make_int2(indices[base] * (N_TOK / 4), __float_as_int(data[base]));
    }
    __syncthreads();

    const uint2* __restrict__ xT2 = (const uint2*)g_xT16;  // 4 bf16 tokens per uint2
    const int w = t >> 6;                  // wave 0..3 -> local row
    const int l = t & 63;                  // lane
    const int tokoff = tg * (TOK_G / 4) + l;   // uint2 index within a col's row

    const int2* __restrict__ p = &s_wi[w * NNZ_ROW];
    float4 acc = make_float4(0.f, 0.f, 0.f, 0.f);
#pragma unroll 16
    for (int k = 0; k < NNZ_ROW; ++k) {
        const int2 wi  = p[k];                                   // uniform ds_read_b64
        const int  off = __builtin_amdgcn_readfirstlane(wi.x);   // pre-scaled col
        const float wt = __int_as_float(__builtin_amdgcn_readfirstlane(wi.y));
        const uint2 u  = xT2[off + tokoff];                      // 512 B/wave, L2
        acc.x += wt * __uint_as_float(u.x << 16);   // token 4l   (low bf16)
        acc.y += wt * __uint_as_float(u.x);         // token 4l+1 (high bf16 + eps)
        acc.z += wt * __uint_as_float(u.y << 16);   // token 4l+2
        acc.w += wt * __uint_as_float(u.y);         // token 4l+3
    }
    // tokens 4l..4l+3 of this group, feature w: one b128 write, conflict-free
    *(float4*)&ytile[w][4 * l] = acc;
    __syncthreads();

    // ---- coalesced store: token n gets features r0..r0+3 (16 B runs) ----
    const int n0 = tg * TOK_G;
#pragma unroll
    for (int i = 0; i < 4; ++i) {
        const int g = t + i * 256;       // 0..1023
        const int n = g >> 2;            // token in tile
        const int f = g & (ROW_G - 1);   // feature in tile
        y[(n0 + n) * OUT_F + r0 + f] = ytile[f][n];
    }
}

// ---------------------------------------------------------------------------
extern "C" void kernel_launch(void* const* d_in, const int* in_sizes, int n_in,
                              void* d_out, int out_size, void* d_ws, size_t ws_size,
                              hipStream_t stream) {
    const float* x       = (const float*)d_in[0];   // [512, 2048] f32
    const float* data    = (const float*)d_in[1];   // [262144] f32
    const int*   indices = (const int*)  d_in[2];   // [262144] i32
    const int*   indptr  = (const int*)  d_in[3];   // [2049] i32
    float*       y       = (float*)d_out;           // [512, 2048] f32

    dim3 tb(32, 8);
    dim3 tg(IN_F / 32, N_TOK / 32);
    transpose_x<<<tg, tb, 0, stream>>>(x);

    dim3 sg(OUT_F / ROW_G, N_TOK / TOK_G);          // 512 x 2 = 1024 blocks
    spmm_csr<<<sg, 256, 0, stream>>>(data, indices, indptr, y);
}